// Round 7
// baseline (3001.142 us; speedup 1.0000x reference)
//
#include <hip/hip_runtime.h>
#include <math.h>

#define N_NODES 2048
#define NET 3
#define NE 65536
#define TE 196608
#define W_IN 256
#define NTGT 512
#define CAP 192
#define GRID 2048
#define NTHR 256

// workspace float offsets
#define OFF_BAR   0
#define OFF_CNT   16
#define OFF_ECOL  2064
#define OFF_EV    395280
#define OFF_XP    1968144
#define OFF_H1    2230288
#define OFF_S0    2492432
#define OFF_DINV  2496528
#define OFF_M1D   2498576
#define OFF_U     2531344
#define OFF_M2D   2596880
#define OFF_V     2727952

__device__ __forceinline__ void gbar(int* cnt) {
    __syncthreads();
    __threadfence();
    if (threadIdx.x == 0) {
        atomicAdd(cnt, 1);
        while (__hip_atomic_load(cnt, __ATOMIC_RELAXED, __HIP_MEMORY_SCOPE_AGENT) < GRID)
            __builtin_amdgcn_s_sleep(2);
    }
    __syncthreads();
    __threadfence();
}

__global__ __launch_bounds__(NTHR, 8) void k_mega(
    const float* __restrict__ X, const float* __restrict__ edge_value,
    const float* __restrict__ conv_w, const float* __restrict__ Ws,
    const float* __restrict__ w1, const float* __restrict__ b1,
    const float* __restrict__ w2, const float* __restrict__ b2,
    const float* __restrict__ lin_w, const float* __restrict__ lin_b,
    const int* __restrict__ ei, const int* __restrict__ tgt,
    float* __restrict__ out, float* __restrict__ ws)
{
    __shared__ float redA[4][64], redP[4][64], rv[4][2], hsh[64];
    const int b = blockIdx.x, tid = threadIdx.x;
    const int wv = tid >> 6, lane = tid & 63;

    int*    bars = (int*)(ws + OFF_BAR);
    int*    cnt  = (int*)(ws + OFF_CNT);
    int*    ecol = (int*)(ws + OFF_ECOL);
    float4* ev4  = (float4*)(ws + OFF_EV);
    float2* Xp2  = (float2*)(ws + OFF_XP);
    float2* H12  = (float2*)(ws + OFF_H1);
    float2* s02  = (float2*)(ws + OFF_S0);
    float*  dinv = ws + OFF_DINV;
    float*  M1d  = ws + OFF_M1D;
    float*  U2   = ws + OFF_U;
    float*  M2d  = ws + OFF_M2D;
    float2* V2   = (float2*)(ws + OFF_V);

    // ================ P0: projection (blocks 0..127) | bucket scatter (blocks 128..895) ================
    if (b < 128) {
        int g = b*NTHR + tid;          // 0..32767
        int d = g & 63;
        int grp = g >> 6;              // 0..511 (4 nodes each)
        const float* w0  = Ws + d;
        const float* w1p = Ws + W_IN*64 + d;
        const float* x0  = X + (grp*4)*W_IN;
        float a00=0.f,a01=0.f,a10=0.f,a11=0.f,a20=0.f,a21=0.f,a30=0.f,a31=0.f;
        for (int f = 0; f < W_IN; ++f) {
            float wa = w0[f*64], wb = w1p[f*64];
            float xa = x0[f], xb_ = x0[W_IN+f], xc = x0[2*W_IN+f], xd = x0[3*W_IN+f];
            a00 += xa*wa;  a01 += xa*wb;
            a10 += xb_*wa; a11 += xb_*wb;
            a20 += xc*wa;  a21 += xc*wb;
            a30 += xd*wa;  a31 += xd*wb;
        }
        Xp2[(grp*4+0)*64 + d] = make_float2(a00, a01);
        Xp2[(grp*4+1)*64 + d] = make_float2(a10, a11);
        Xp2[(grp*4+2)*64 + d] = make_float2(a20, a21);
        Xp2[(grp*4+3)*64 + d] = make_float2(a30, a31);
    } else if (b < 896) {
        float f00[3], f01[3], f10[3], f11[3];
        #pragma unroll
        for (int i = 0; i < 4; i++) {
            float a = conv_w[i*3+0], bb = conv_w[i*3+1], cc = conv_w[i*3+2];
            float m = fmaxf(a, fmaxf(bb, cc));
            float ea = expf(a-m), eb = expf(bb-m), ec = expf(cc-m);
            float s = 1.0f/(ea + eb + ec);
            float* dst = (i==0)?f00:((i==1)?f01:((i==2)?f10:f11));
            dst[0] = ea*s; dst[1] = eb*s; dst[2] = ec*s;
        }
        int e = (b-128)*NTHR + tid;    // exactly covers TE = 768*256
        int t = e >> 16, idx = e & 0xFFFF;
        int row = ei[t*2*NE + idx];
        int col = ei[t*2*NE + NE + idx];
        float ev = edge_value[e];
        int pos = atomicAdd(&cnt[row], 1);
        if (pos < CAP) {
            ecol[row*CAP + pos] = col;
            ev4[row*CAP + pos] = make_float4(ev*f00[t], ev*f01[t], ev*f10[t], ev*f11[t]);
        }
    }
    gbar(&bars[0]);

    const int r = b;
    const int len = min(cnt[r], CAP), base = r*CAP;
    const int q0 = (len*wv) >> 2, q1 = (len*(wv+1)) >> 2;

    // ================ P1: H1 = M0 @ Xp (both ch), s0 = rowsums ================
    {
        float a0=0.f,a1=0.f,p0=0.f,p1=0.f, vs0=0.f, vs1=0.f;
        int j = q0;
        for (; j+2 <= q1; j += 2) {
            int cA = ecol[base+j], cB = ecol[base+j+1];
            float4 eA = ev4[base+j], eB = ev4[base+j+1];
            float2 xA = Xp2[cA*64+lane], xB = Xp2[cB*64+lane];
            a0 += eA.x*xA.x; p0 += eA.y*xA.y;
            a1 += eB.x*xB.x; p1 += eB.y*xB.y;
            vs0 += eA.x + eB.x; vs1 += eA.y + eB.y;
        }
        if (j < q1) {
            int cA = ecol[base+j]; float4 eA = ev4[base+j];
            float2 xA = Xp2[cA*64+lane];
            a0 += eA.x*xA.x; p0 += eA.y*xA.y;
            vs0 += eA.x; vs1 += eA.y;
        }
        redA[wv][lane] = a0+a1; redP[wv][lane] = p0+p1;
        if (lane == 0) { rv[wv][0] = vs0; rv[wv][1] = vs1; }
        __syncthreads();
        if (wv == 0) {
            float A = redA[0][lane]+redA[1][lane]+redA[2][lane]+redA[3][lane];
            float P = redP[0][lane]+redP[1][lane]+redP[2][lane]+redP[3][lane];
            H12[r*64 + lane] = make_float2(A, P);
            if (lane == 0)
                s02[r] = make_float2(rv[0][0]+rv[1][0]+rv[2][0]+rv[3][0],
                                     rv[0][1]+rv[1][1]+rv[2][1]+rv[3][1]);
        }
    }
    gbar(&bars[1]);

    // ================ P2: H2 = M1 @ H1, s1 = M1 @ s0, blend + dinv + M1d ================
    {
        float a0=0.f,a1=0.f,p0=0.f,p1=0.f, sv0=0.f, sv1=0.f;
        int j = q0;
        for (; j+2 <= q1; j += 2) {
            int cA = ecol[base+j], cB = ecol[base+j+1];
            float4 eA = ev4[base+j], eB = ev4[base+j+1];
            float2 xA = H12[cA*64+lane], xB = H12[cB*64+lane];
            float2 sA = s02[cA], sB = s02[cB];
            a0 += eA.z*xA.x; p0 += eA.w*xA.y;
            a1 += eB.z*xB.x; p1 += eB.w*xB.y;
            sv0 += eA.z*sA.x + eB.z*sB.x;
            sv1 += eA.w*sA.y + eB.w*sB.y;
        }
        if (j < q1) {
            int cA = ecol[base+j]; float4 eA = ev4[base+j];
            float2 xA = H12[cA*64+lane]; float2 sA = s02[cA];
            a0 += eA.z*xA.x; p0 += eA.w*xA.y;
            sv0 += eA.z*sA.x; sv1 += eA.w*sA.y;
        }
        __syncthreads();   // protect LDS reuse
        redA[wv][lane] = a0+a1; redP[wv][lane] = p0+p1;
        if (lane == 0) { rv[wv][0] = sv0; rv[wv][1] = sv1; }
        __syncthreads();
        if (wv == 0) {
            float A = redA[0][lane]+redA[1][lane]+redA[2][lane]+redA[3][lane];
            float P = redP[0][lane]+redP[1][lane]+redP[2][lane]+redP[3][lane];
            float SV0 = rv[0][0]+rv[1][0]+rv[2][0]+rv[3][0];
            float SV1 = rv[0][1]+rv[1][1]+rv[2][1]+rv[3][1];
            float dv = rsqrtf(1.0f + SV0 + SV1);
            float2 x = Xp2[r*64 + lane];
            float hc = 0.5f*(fmaxf(0.5f*(x.x + A), 0.f) + fmaxf(0.5f*(x.y + P), 0.f));
            if (lane == 0) dinv[r] = dv;
            int jj = lane & 15, quarter = lane >> 4;
            float acc = 0.f;
            #pragma unroll
            for (int k = 0; k < 16; k++) {
                int d = quarter*16 + k;
                acc += __shfl(hc, d) * w1[d*16 + jj];
            }
            acc += __shfl_xor(acc, 16);
            acc += __shfl_xor(acc, 32);
            if (lane < 16) M1d[r*16 + lane] = dv * acc;
        }
    }
    gbar(&bars[2]);

    // ================ P3: U = M0 @ M1d (per channel) ================
    {
        int d = lane & 15, ch = (lane >> 4) & 1, ep = lane >> 5;
        float acc = 0.f;
        int j = q0;
        for (; j+2 <= q1; j += 2) {
            int jj = base + j + ep;
            int c = ecol[jj]; float4 e = ev4[jj];
            acc += (ch ? e.y : e.x) * M1d[c*16 + d];
        }
        if (j < q1 && ep == 0) {
            int c = ecol[base+j]; float4 e = ev4[base+j];
            acc += (ch ? e.y : e.x) * M1d[c*16 + d];
        }
        acc += __shfl_xor(acc, 32);
        __syncthreads();
        if (lane < 32) redA[0][wv*32 + lane] = acc;   // reuse redA as [4][32]
        __syncthreads();
        if (wv == 0 && lane < 32) {
            float s = redA[0][lane]+redA[0][32+lane]+redA[0][64+lane]+redA[0][96+lane];
            U2[r*32 + d*2 + ch] = s;
        }
    }
    gbar(&bars[3]);

    // ================ P4: P = M1 @ U, h1 = relu, M2d = dinv*(h1@w2) ================
    {
        int d = lane & 15, ch = (lane >> 4) & 1, ep = lane >> 5;
        float acc = 0.f;
        int j = q0;
        for (; j+2 <= q1; j += 2) {
            int jj = base + j + ep;
            int c = ecol[jj]; float4 e = ev4[jj];
            acc += (ch ? e.w : e.z) * U2[c*32 + d*2 + ch];
        }
        if (j < q1 && ep == 0) {
            int c = ecol[base+j]; float4 e = ev4[base+j];
            acc += (ch ? e.w : e.z) * U2[c*32 + d*2 + ch];
        }
        acc += __shfl_xor(acc, 32);
        __syncthreads();
        if (lane < 32) redA[0][wv*32 + lane] = acc;
        __syncthreads();
        if (wv == 0) {
            float Pv = redA[0][lane&31]+redA[0][32+(lane&31)]+redA[0][64+(lane&31)]+redA[0][96+(lane&31)];
            Pv += __shfl_xor(Pv, 16);
            float dv = dinv[r];
            float hv = fmaxf(dv*(Pv + M1d[r*16 + (lane&15)]) + b1[lane&15], 0.f);
            float m2 = 0.f;
            #pragma unroll
            for (int k = 0; k < 16; k++) m2 += __shfl(hv, k) * w2[k*64 + lane];
            M2d[r*64 + lane] = dv * m2;
        }
    }
    gbar(&bars[4]);

    // ================ P5: V = M0 @ M2d (both ch) ================
    {
        float a0=0.f,a1=0.f,p0=0.f,p1=0.f;
        int j = q0;
        for (; j+2 <= q1; j += 2) {
            int cA = ecol[base+j], cB = ecol[base+j+1];
            float4 eA = ev4[base+j], eB = ev4[base+j+1];
            float xA = M2d[cA*64+lane], xB = M2d[cB*64+lane];
            a0 += eA.x*xA; p0 += eA.y*xA;
            a1 += eB.x*xB; p1 += eB.y*xB;
        }
        if (j < q1) {
            int cA = ecol[base+j]; float4 eA = ev4[base+j];
            float xA = M2d[cA*64+lane];
            a0 += eA.x*xA; p0 += eA.y*xA;
        }
        __syncthreads();
        redA[wv][lane] = a0+a1; redP[wv][lane] = p0+p1;
        __syncthreads();
        if (wv == 0) {
            float A = redA[0][lane]+redA[1][lane]+redA[2][lane]+redA[3][lane];
            float P = redP[0][lane]+redP[1][lane]+redP[2][lane]+redP[3][lane];
            V2[r*64 + lane] = make_float2(A, P);
        }
    }
    gbar(&bars[5]);

    // ================ P6: R = M1 @ V, log_softmax, head ================
    {
        float a0=0.f, a1=0.f;
        int j = q0;
        for (; j+2 <= q1; j += 2) {
            int cA = ecol[base+j], cB = ecol[base+j+1];
            float4 eA = ev4[base+j], eB = ev4[base+j+1];
            float2 xA = V2[cA*64+lane], xB = V2[cB*64+lane];
            a0 += eA.z*xA.x + eA.w*xA.y;
            a1 += eB.z*xB.x + eB.w*xB.y;
        }
        if (j < q1) {
            int cA = ecol[base+j]; float4 eA = ev4[base+j];
            float2 xA = V2[cA*64+lane];
            a0 += eA.z*xA.x + eA.w*xA.y;
        }
        __syncthreads();
        redA[wv][lane] = a0+a1;
        __syncthreads();
        if (wv == 0) {
            float S = redA[0][lane]+redA[1][lane]+redA[2][lane]+redA[3][lane];
            float v = dinv[r]*(S + M2d[r*64 + lane]) + b2[lane];
            float mx = v;
            #pragma unroll
            for (int o = 1; o < 64; o <<= 1) mx = fmaxf(mx, __shfl_xor(mx, o));
            float s = expf(v - mx);
            #pragma unroll
            for (int o = 1; o < 64; o <<= 1) s += __shfl_xor(s, o);
            hsh[lane] = v - mx - logf(s);
        }
        __syncthreads();
        for (int i = tid; i < NTGT; i += NTHR) {
            if (tgt[i] == r) {
                #pragma unroll 4
                for (int k = 0; k < 16; k++) {
                    float acc = 0.f;
                    #pragma unroll
                    for (int dd = 0; dd < 64; dd++) acc += hsh[dd] * lin_w[dd*16 + k];
                    out[i*16 + k] = acc + lin_b[k];
                }
            }
        }
    }
}

// ---------------- launch ----------------
extern "C" void kernel_launch(void* const* d_in, const int* in_sizes, int n_in,
                              void* d_out, int out_size, void* d_ws, size_t ws_size,
                              hipStream_t stream) {
    const float* X          = (const float*)d_in[0];
    const float* edge_value = (const float*)d_in[1];
    const float* conv_w     = (const float*)d_in[2];
    const float* Ws         = (const float*)d_in[3];
    const float* w1         = (const float*)d_in[4];
    const float* b1         = (const float*)d_in[5];
    const float* w2         = (const float*)d_in[6];
    const float* b2         = (const float*)d_in[7];
    const float* lin_w      = (const float*)d_in[8];
    const float* lin_b      = (const float*)d_in[9];
    const int*   ei         = (const int*)d_in[10];
    const int*   tgt        = (const int*)d_in[11];
    float* ws = (float*)d_ws;

    hipMemsetAsync(ws, 0, (16 + N_NODES)*sizeof(int), stream);   // bars + cnt
    k_mega<<<GRID, NTHR, 0, stream>>>(X, edge_value, conv_w, Ws, w1, b1, w2, b2,
                                      lin_w, lin_b, ei, tgt, (float*)d_out, ws);
}

// Round 14
// 1949.165 us; speedup vs baseline: 1.5397x; 1.5397x over previous
//
#include <hip/hip_runtime.h>
#include <math.h>

#define N_NODES 2048
#define NET 3
#define NE 65536
#define TE 196608
#define W_IN 256
#define NTGT 512
#define CAP 192
#define NCAP (N_NODES*CAP)   /* 393216 */
#define GRID 1024
#define NTHR 256
#define NGRP 32
#define FSTRIDE 16           /* 16 ints = 64 B per flag line */

// int-index layout of sync area at start of ws
#define I_FLAG 0             /* [1024] x FSTRIDE */
#define I_REL  16384         /* [32] x FSTRIDE   */
#define I_CNT  16896         /* [2048]           */
#define SYNC_INTS 18944
// float-index offsets for data (start right after sync area; 16B aligned)
#define OFF_ECOL  18944      /* NCAP ints           */
#define OFF_EV    412160     /* NCAP float4 = 4*NCAP */
#define OFF_XP    1985024    /* 2048*64 float2       */
#define OFF_H1    2247168    /* 2048*64 float2       */
#define OFF_S0    2509312    /* 2048 float2          */
#define OFF_DINV  2513408    /* 2048                 */
#define OFF_M1D   2515456    /* 2048*16              */
#define OFF_U     2548224    /* 2048*32              */
#define OFF_M2D   2613760    /* 2048*64              */
#define OFF_V     2744832    /* 2048*64 float2       */

__device__ __forceinline__ void gbar(int* isync, int epoch, int b) {
    __syncthreads();
    __threadfence();   // release: all threads drain/flush their phase's writes
    if (threadIdx.x == 0) {
        __hip_atomic_store(isync + I_FLAG + b*FSTRIDE, epoch,
                           __ATOMIC_RELEASE, __HIP_MEMORY_SCOPE_AGENT);
    }
    if (b == 0) {
        // master: 256 threads sweep 1024 padded flags (4 each, parallel lines)
        int t = threadIdx.x;
        for (int k = t; k < GRID; k += NTHR) {
            while (__hip_atomic_load(isync + I_FLAG + k*FSTRIDE,
                                     __ATOMIC_ACQUIRE, __HIP_MEMORY_SCOPE_AGENT) < epoch)
                __builtin_amdgcn_s_sleep(4);
        }
        __syncthreads();
        if (t < NGRP)
            __hip_atomic_store(isync + I_REL + t*FSTRIDE, epoch,
                               __ATOMIC_RELEASE, __HIP_MEMORY_SCOPE_AGENT);
    } else {
        if (threadIdx.x == 0) {
            int g = b >> 5;            // 32 blocks per group
            while (__hip_atomic_load(isync + I_REL + g*FSTRIDE,
                                     __ATOMIC_ACQUIRE, __HIP_MEMORY_SCOPE_AGENT) < epoch)
                __builtin_amdgcn_s_sleep(8);
        }
    }
    __syncthreads();
    __threadfence();       // acquire side
}

__global__ __launch_bounds__(NTHR, 4) void k_mega(
    const float* __restrict__ X, const float* __restrict__ edge_value,
    const float* __restrict__ conv_w, const float* __restrict__ Ws,
    const float* __restrict__ w1, const float* __restrict__ b1,
    const float* __restrict__ w2, const float* __restrict__ b2,
    const float* __restrict__ lin_w, const float* __restrict__ lin_b,
    const int* __restrict__ ei, const int* __restrict__ tgt,
    float* __restrict__ out, float* __restrict__ ws)
{
    __shared__ float redA[4][64], redP[4][64], rv[4][2], hsh[64];
    const int b = blockIdx.x, tid = threadIdx.x;
    const int wv = tid >> 6, lane = tid & 63;

    int*    isync = (int*)ws;
    int*    cnt  = isync + I_CNT;
    int*    ecol = (int*)(ws + OFF_ECOL);
    float4* ev4  = (float4*)(ws + OFF_EV);
    float2* Xp2  = (float2*)(ws + OFF_XP);
    float2* H12  = (float2*)(ws + OFF_H1);
    float2* s02  = (float2*)(ws + OFF_S0);
    float*  dinv = ws + OFF_DINV;
    float*  M1d  = ws + OFF_M1D;
    float*  U2   = ws + OFF_U;
    float*  M2d  = ws + OFF_M2D;
    float2* V2   = (float2*)(ws + OFF_V);

    // ================ P0: projection (blocks 0..127) | bucket scatter (blocks 128..895) ================
    if (b < 128) {
        int g = b*NTHR + tid;          // 0..32767
        int d = g & 63;
        int grp = g >> 6;              // 0..511 (4 nodes each)
        const float* w0  = Ws + d;
        const float* w1p = Ws + W_IN*64 + d;
        const float* x0  = X + (grp*4)*W_IN;
        float a00=0.f,a01=0.f,a10=0.f,a11=0.f,a20=0.f,a21=0.f,a30=0.f,a31=0.f;
        for (int f = 0; f < W_IN; ++f) {
            float wa = w0[f*64], wb = w1p[f*64];
            float xa = x0[f], xb_ = x0[W_IN+f], xc = x0[2*W_IN+f], xd = x0[3*W_IN+f];
            a00 += xa*wa;  a01 += xa*wb;
            a10 += xb_*wa; a11 += xb_*wb;
            a20 += xc*wa;  a21 += xc*wb;
            a30 += xd*wa;  a31 += xd*wb;
        }
        Xp2[(grp*4+0)*64 + d] = make_float2(a00, a01);
        Xp2[(grp*4+1)*64 + d] = make_float2(a10, a11);
        Xp2[(grp*4+2)*64 + d] = make_float2(a20, a21);
        Xp2[(grp*4+3)*64 + d] = make_float2(a30, a31);
    } else if (b < 896) {
        float f00[3], f01[3], f10[3], f11[3];
        #pragma unroll
        for (int i = 0; i < 4; i++) {
            float a = conv_w[i*3+0], bb = conv_w[i*3+1], cc = conv_w[i*3+2];
            float m = fmaxf(a, fmaxf(bb, cc));
            float ea = expf(a-m), eb = expf(bb-m), ec = expf(cc-m);
            float s = 1.0f/(ea + eb + ec);
            float* dst = (i==0)?f00:((i==1)?f01:((i==2)?f10:f11));
            dst[0] = ea*s; dst[1] = eb*s; dst[2] = ec*s;
        }
        int e = (b-128)*NTHR + tid;    // exactly covers TE = 768*256
        int t = e >> 16, idx = e & 0xFFFF;
        int row = ei[t*2*NE + idx];
        int col = ei[t*2*NE + NE + idx];
        float ev = edge_value[e];
        int pos = atomicAdd(&cnt[row], 1);
        if (pos < CAP) {
            ecol[row*CAP + pos] = col;
            ev4[row*CAP + pos] = make_float4(ev*f00[t], ev*f01[t], ev*f10[t], ev*f11[t]);
        }
    }
    gbar(isync, 1, b);

    // ================ P1: H1 = M0 @ Xp (both ch), s0 = rowsums ================
    for (int rr = 0; rr < 2; ++rr) {
        int r = b*2 + rr;
        int len = min(cnt[r], CAP), base = r*CAP;
        int q0 = (len*wv) >> 2, q1 = (len*(wv+1)) >> 2;
        float a0=0.f,a1=0.f,p0=0.f,p1=0.f, vs0=0.f, vs1=0.f;
        int j = q0;
        for (; j+2 <= q1; j += 2) {
            int cA = ecol[base+j], cB = ecol[base+j+1];
            float4 eA = ev4[base+j], eB = ev4[base+j+1];
            float2 xA = Xp2[cA*64+lane], xB = Xp2[cB*64+lane];
            a0 += eA.x*xA.x; p0 += eA.y*xA.y;
            a1 += eB.x*xB.x; p1 += eB.y*xB.y;
            vs0 += eA.x + eB.x; vs1 += eA.y + eB.y;
        }
        if (j < q1) {
            int cA = ecol[base+j]; float4 eA = ev4[base+j];
            float2 xA = Xp2[cA*64+lane];
            a0 += eA.x*xA.x; p0 += eA.y*xA.y;
            vs0 += eA.x; vs1 += eA.y;
        }
        redA[wv][lane] = a0+a1; redP[wv][lane] = p0+p1;
        if (lane == 0) { rv[wv][0] = vs0; rv[wv][1] = vs1; }
        __syncthreads();
        if (wv == 0) {
            float A = redA[0][lane]+redA[1][lane]+redA[2][lane]+redA[3][lane];
            float P = redP[0][lane]+redP[1][lane]+redP[2][lane]+redP[3][lane];
            H12[r*64 + lane] = make_float2(A, P);
            if (lane == 0)
                s02[r] = make_float2(rv[0][0]+rv[1][0]+rv[2][0]+rv[3][0],
                                     rv[0][1]+rv[1][1]+rv[2][1]+rv[3][1]);
        }
        __syncthreads();
    }
    gbar(isync, 2, b);

    // ================ P2: H2 = M1 @ H1, s1 = M1 @ s0, blend + dinv + M1d ================
    for (int rr = 0; rr < 2; ++rr) {
        int r = b*2 + rr;
        int len = min(cnt[r], CAP), base = r*CAP;
        int q0 = (len*wv) >> 2, q1 = (len*(wv+1)) >> 2;
        float a0=0.f,a1=0.f,p0=0.f,p1=0.f, sv0=0.f, sv1=0.f;
        int j = q0;
        for (; j+2 <= q1; j += 2) {
            int cA = ecol[base+j], cB = ecol[base+j+1];
            float4 eA = ev4[base+j], eB = ev4[base+j+1];
            float2 xA = H12[cA*64+lane], xB = H12[cB*64+lane];
            float2 sA = s02[cA], sB = s02[cB];
            a0 += eA.z*xA.x; p0 += eA.w*xA.y;
            a1 += eB.z*xB.x; p1 += eB.w*xB.y;
            sv0 += eA.z*sA.x + eB.z*sB.x;
            sv1 += eA.w*sA.y + eB.w*sB.y;
        }
        if (j < q1) {
            int cA = ecol[base+j]; float4 eA = ev4[base+j];
            float2 xA = H12[cA*64+lane]; float2 sA = s02[cA];
            a0 += eA.z*xA.x; p0 += eA.w*xA.y;
            sv0 += eA.z*sA.x; sv1 += eA.w*sA.y;
        }
        __syncthreads();
        redA[wv][lane] = a0+a1; redP[wv][lane] = p0+p1;
        if (lane == 0) { rv[wv][0] = sv0; rv[wv][1] = sv1; }
        __syncthreads();
        if (wv == 0) {
            float A = redA[0][lane]+redA[1][lane]+redA[2][lane]+redA[3][lane];
            float P = redP[0][lane]+redP[1][lane]+redP[2][lane]+redP[3][lane];
            float SV0 = rv[0][0]+rv[1][0]+rv[2][0]+rv[3][0];
            float SV1 = rv[0][1]+rv[1][1]+rv[2][1]+rv[3][1];
            float dv = rsqrtf(1.0f + SV0 + SV1);
            float2 x = Xp2[r*64 + lane];
            float hc = 0.5f*(fmaxf(0.5f*(x.x + A), 0.f) + fmaxf(0.5f*(x.y + P), 0.f));
            if (lane == 0) dinv[r] = dv;
            int jj = lane & 15, quarter = lane >> 4;
            float acc = 0.f;
            #pragma unroll
            for (int k = 0; k < 16; k++) {
                int d = quarter*16 + k;
                acc += __shfl(hc, d) * w1[d*16 + jj];
            }
            acc += __shfl_xor(acc, 16);
            acc += __shfl_xor(acc, 32);
            if (lane < 16) M1d[r*16 + lane] = dv * acc;
        }
        __syncthreads();
    }
    gbar(isync, 3, b);

    // ================ P3: U = M0 @ M1d (per channel) ================
    for (int rr = 0; rr < 2; ++rr) {
        int r = b*2 + rr;
        int len = min(cnt[r], CAP), base = r*CAP;
        int q0 = (len*wv) >> 2, q1 = (len*(wv+1)) >> 2;
        int d = lane & 15, ch = (lane >> 4) & 1, ep = lane >> 5;
        float acc = 0.f;
        int j = q0;
        for (; j+2 <= q1; j += 2) {
            int jj = base + j + ep;
            int c = ecol[jj]; float4 e = ev4[jj];
            acc += (ch ? e.y : e.x) * M1d[c*16 + d];
        }
        if (j < q1 && ep == 0) {
            int c = ecol[base+j]; float4 e = ev4[base+j];
            acc += (ch ? e.y : e.x) * M1d[c*16 + d];
        }
        acc += __shfl_xor(acc, 32);
        __syncthreads();
        if (lane < 32) redA[0][wv*32 + lane] = acc;
        __syncthreads();
        if (wv == 0 && lane < 32) {
            float s = redA[0][lane]+redA[0][32+lane]+redA[0][64+lane]+redA[0][96+lane];
            U2[r*32 + d*2 + ch] = s;
        }
        __syncthreads();
    }
    gbar(isync, 4, b);

    // ================ P4: P = M1 @ U, h1 = relu, M2d = dinv*(h1@w2) ================
    for (int rr = 0; rr < 2; ++rr) {
        int r = b*2 + rr;
        int len = min(cnt[r], CAP), base = r*CAP;
        int q0 = (len*wv) >> 2, q1 = (len*(wv+1)) >> 2;
        int d = lane & 15, ch = (lane >> 4) & 1, ep = lane >> 5;
        float acc = 0.f;
        int j = q0;
        for (; j+2 <= q1; j += 2) {
            int jj = base + j + ep;
            int c = ecol[jj]; float4 e = ev4[jj];
            acc += (ch ? e.w : e.z) * U2[c*32 + d*2 + ch];
        }
        if (j < q1 && ep == 0) {
            int c = ecol[base+j]; float4 e = ev4[base+j];
            acc += (ch ? e.w : e.z) * U2[c*32 + d*2 + ch];
        }
        acc += __shfl_xor(acc, 32);
        __syncthreads();
        if (lane < 32) redA[0][wv*32 + lane] = acc;
        __syncthreads();
        if (wv == 0) {
            float Pv = redA[0][lane&31]+redA[0][32+(lane&31)]+redA[0][64+(lane&31)]+redA[0][96+(lane&31)];
            Pv += __shfl_xor(Pv, 16);
            float dv = dinv[r];
            float hv = fmaxf(dv*(Pv + M1d[r*16 + (lane&15)]) + b1[lane&15], 0.f);
            float m2 = 0.f;
            #pragma unroll
            for (int k = 0; k < 16; k++) m2 += __shfl(hv, k) * w2[k*64 + lane];
            M2d[r*64 + lane] = dv * m2;
        }
        __syncthreads();
    }
    gbar(isync, 5, b);

    // ================ P5: V = M0 @ M2d (both ch) ================
    for (int rr = 0; rr < 2; ++rr) {
        int r = b*2 + rr;
        int len = min(cnt[r], CAP), base = r*CAP;
        int q0 = (len*wv) >> 2, q1 = (len*(wv+1)) >> 2;
        float a0=0.f,a1=0.f,p0=0.f,p1=0.f;
        int j = q0;
        for (; j+2 <= q1; j += 2) {
            int cA = ecol[base+j], cB = ecol[base+j+1];
            float4 eA = ev4[base+j], eB = ev4[base+j+1];
            float xA = M2d[cA*64+lane], xB = M2d[cB*64+lane];
            a0 += eA.x*xA; p0 += eA.y*xA;
            a1 += eB.x*xB; p1 += eB.y*xB;
        }
        if (j < q1) {
            int cA = ecol[base+j]; float4 eA = ev4[base+j];
            float xA = M2d[cA*64+lane];
            a0 += eA.x*xA; p0 += eA.y*xA;
        }
        __syncthreads();
        redA[wv][lane] = a0+a1; redP[wv][lane] = p0+p1;
        __syncthreads();
        if (wv == 0) {
            float A = redA[0][lane]+redA[1][lane]+redA[2][lane]+redA[3][lane];
            float P = redP[0][lane]+redP[1][lane]+redP[2][lane]+redP[3][lane];
            V2[r*64 + lane] = make_float2(A, P);
        }
        __syncthreads();
    }
    gbar(isync, 6, b);

    // ================ P6: R = M1 @ V, log_softmax, head ================
    for (int rr = 0; rr < 2; ++rr) {
        int r = b*2 + rr;
        int len = min(cnt[r], CAP), base = r*CAP;
        int q0 = (len*wv) >> 2, q1 = (len*(wv+1)) >> 2;
        float a0=0.f, a1=0.f;
        int j = q0;
        for (; j+2 <= q1; j += 2) {
            int cA = ecol[base+j], cB = ecol[base+j+1];
            float4 eA = ev4[base+j], eB = ev4[base+j+1];
            float2 xA = V2[cA*64+lane], xB = V2[cB*64+lane];
            a0 += eA.z*xA.x + eA.w*xA.y;
            a1 += eB.z*xB.x + eB.w*xB.y;
        }
        if (j < q1) {
            int cA = ecol[base+j]; float4 eA = ev4[base+j];
            float2 xA = V2[cA*64+lane];
            a0 += eA.z*xA.x + eA.w*xA.y;
        }
        __syncthreads();
        redA[wv][lane] = a0+a1;
        __syncthreads();
        if (wv == 0) {
            float S = redA[0][lane]+redA[1][lane]+redA[2][lane]+redA[3][lane];
            float v = dinv[r]*(S + M2d[r*64 + lane]) + b2[lane];
            float mx = v;
            #pragma unroll
            for (int o = 1; o < 64; o <<= 1) mx = fmaxf(mx, __shfl_xor(mx, o));
            float s = expf(v - mx);
            #pragma unroll
            for (int o = 1; o < 64; o <<= 1) s += __shfl_xor(s, o);
            hsh[lane] = v - mx - logf(s);
        }
        __syncthreads();
        for (int i = tid; i < NTGT; i += NTHR) {
            if (tgt[i] == r) {
                #pragma unroll 4
                for (int k = 0; k < 16; k++) {
                    float acc = 0.f;
                    #pragma unroll
                    for (int dd = 0; dd < 64; dd++) acc += hsh[dd] * lin_w[dd*16 + k];
                    out[i*16 + k] = acc + lin_b[k];
                }
            }
        }
        __syncthreads();
    }
}

// ---------------- launch ----------------
extern "C" void kernel_launch(void* const* d_in, const int* in_sizes, int n_in,
                              void* d_out, int out_size, void* d_ws, size_t ws_size,
                              hipStream_t stream) {
    const float* X          = (const float*)d_in[0];
    const float* edge_value = (const float*)d_in[1];
    const float* conv_w     = (const float*)d_in[2];
    const float* Ws         = (const float*)d_in[3];
    const float* w1         = (const float*)d_in[4];
    const float* b1         = (const float*)d_in[5];
    const float* w2         = (const float*)d_in[6];
    const float* b2         = (const float*)d_in[7];
    const float* lin_w      = (const float*)d_in[8];
    const float* lin_b      = (const float*)d_in[9];
    const int*   ei         = (const int*)d_in[10];
    const int*   tgt        = (const int*)d_in[11];
    float* ws = (float*)d_ws;

    hipMemsetAsync(ws, 0, SYNC_INTS*sizeof(int), stream);   // flags + rel + cnt
    k_mega<<<GRID, NTHR, 0, stream>>>(X, edge_value, conv_w, Ws, w1, b1, w2, b2,
                                      lin_w, lin_b, ei, tgt, (float*)d_out, ws);
}

// Round 15
// 220.930 us; speedup vs baseline: 13.5841x; 8.8225x over previous
//
#include <hip/hip_runtime.h>
#include <math.h>

#define N_NODES 2048
#define NET 3
#define NE 65536
#define TE 196608
#define W_IN 256
#define NTGT 512
#define CAP 192

// workspace float offsets
#define OFF_CNT   0
#define OFF_ECOL  2048
#define OFF_EV    395264
#define OFF_XP    1968128
#define OFF_H1    2230272
#define OFF_S0    2492416
#define OFF_DINV  2496512
#define OFF_M1D   2498560
#define OFF_U     2531328
#define OFF_M2D   2596864
#define OFF_V     2727936

// ---------------- init: bucket-scatter (blocks 0..767, 1 edge/thread) + projection (768..895) ----------------
__global__ __launch_bounds__(256) void k_init(
    const float* __restrict__ conv_w, const float* __restrict__ X,
    const float* __restrict__ Ws, const int* __restrict__ ei,
    const float* __restrict__ edge_value,
    int* __restrict__ cnt, int* __restrict__ ecol, float4* __restrict__ ev4,
    float2* __restrict__ Xp2) {
    int b = blockIdx.x, tid = threadIdx.x;
    if (b < 768) {
        float f00[3], f01[3], f10[3], f11[3];
        #pragma unroll
        for (int i = 0; i < 4; i++) {
            float a = conv_w[i*3+0], bb = conv_w[i*3+1], cc = conv_w[i*3+2];
            float m = fmaxf(a, fmaxf(bb, cc));
            float ea = expf(a-m), eb = expf(bb-m), ec = expf(cc-m);
            float s = 1.0f/(ea + eb + ec);
            float* dst = (i==0)?f00:((i==1)?f01:((i==2)?f10:f11));
            dst[0] = ea*s; dst[1] = eb*s; dst[2] = ec*s;
        }
        int e = b*256 + tid;           // exactly covers TE = 768*256
        int t = e >> 16, idx = e & 0xFFFF;
        int row = ei[t*2*NE + idx];
        int col = ei[t*2*NE + NE + idx];
        float ev = edge_value[e];
        int pos = atomicAdd(&cnt[row], 1);
        if (pos < CAP) {
            ecol[row*CAP + pos] = col;
            ev4[row*CAP + pos] = make_float4(ev*f00[t], ev*f01[t], ev*f10[t], ev*f11[t]);
        }
    } else {
        int g = (b-768)*256 + tid;     // 0..32767
        int d = g & 63;
        int grp = g >> 6;              // 0..511 (4 nodes each)
        const float* w0  = Ws + d;
        const float* w1p = Ws + W_IN*64 + d;
        const float* x0  = X + (grp*4)*W_IN;
        float a00=0.f,a01=0.f,a10=0.f,a11=0.f,a20=0.f,a21=0.f,a30=0.f,a31=0.f;
        for (int f = 0; f < W_IN; ++f) {
            float wa = w0[f*64], wb = w1p[f*64];
            float xa = x0[f], xb_ = x0[W_IN+f], xc = x0[2*W_IN+f], xd = x0[3*W_IN+f];
            a00 += xa*wa;  a01 += xa*wb;
            a10 += xb_*wa; a11 += xb_*wb;
            a20 += xc*wa;  a21 += xc*wb;
            a30 += xd*wa;  a31 += xd*wb;
        }
        Xp2[(grp*4+0)*64 + d] = make_float2(a00, a01);
        Xp2[(grp*4+1)*64 + d] = make_float2(a10, a11);
        Xp2[(grp*4+2)*64 + d] = make_float2(a20, a21);
        Xp2[(grp*4+3)*64 + d] = make_float2(a30, a31);
    }
}

// ---------------- H pass 1: H1 = M0 @ Xp (both ch), s0 = rowsums of M0 ----------------
__global__ __launch_bounds__(256) void k_h0(
    const int* __restrict__ cnt, const int* __restrict__ ecol,
    const float4* __restrict__ ev4, const float2* __restrict__ Xp2,
    float2* __restrict__ H12, float2* __restrict__ s02) {
    __shared__ float redA[4][64], redP[4][64], rv[4][2];
    int r = blockIdx.x;
    int wv = threadIdx.x >> 6, lane = threadIdx.x & 63;
    int len = min(cnt[r], CAP), base = r*CAP;
    int q0 = (len*wv) >> 2, q1 = (len*(wv+1)) >> 2;
    float a0=0.f,a1=0.f,p0=0.f,p1=0.f, vs0=0.f, vs1=0.f;
    int j = q0;
    for (; j+2 <= q1; j += 2) {
        int cA = ecol[base+j], cB = ecol[base+j+1];
        float4 eA = ev4[base+j], eB = ev4[base+j+1];
        float2 xA = Xp2[cA*64+lane], xB = Xp2[cB*64+lane];
        a0 += eA.x*xA.x; p0 += eA.y*xA.y;
        a1 += eB.x*xB.x; p1 += eB.y*xB.y;
        vs0 += eA.x + eB.x; vs1 += eA.y + eB.y;
    }
    if (j < q1) {
        int cA = ecol[base+j]; float4 eA = ev4[base+j];
        float2 xA = Xp2[cA*64+lane];
        a0 += eA.x*xA.x; p0 += eA.y*xA.y;
        vs0 += eA.x; vs1 += eA.y;
    }
    redA[wv][lane] = a0+a1; redP[wv][lane] = p0+p1;
    if (lane == 0) { rv[wv][0] = vs0; rv[wv][1] = vs1; }
    __syncthreads();
    if (wv == 0) {
        float A = redA[0][lane]+redA[1][lane]+redA[2][lane]+redA[3][lane];
        float P = redP[0][lane]+redP[1][lane]+redP[2][lane]+redP[3][lane];
        H12[r*64 + lane] = make_float2(A, P);
        if (lane == 0)
            s02[r] = make_float2(rv[0][0]+rv[1][0]+rv[2][0]+rv[3][0],
                                 rv[0][1]+rv[1][1]+rv[2][1]+rv[3][1]);
    }
}

// ---------------- H pass 2 fused: H2 = M1 @ H1, s1 = M1 @ s0, blend + dinv + M1d ----------------
__global__ __launch_bounds__(256) void k_h1(
    const int* __restrict__ cnt, const int* __restrict__ ecol,
    const float4* __restrict__ ev4, const float2* __restrict__ H12,
    const float2* __restrict__ s02, const float2* __restrict__ Xp2,
    const float* __restrict__ w1, float* __restrict__ dinv, float* __restrict__ M1d) {
    __shared__ float redA[4][64], redP[4][64], rv[4][2];
    int r = blockIdx.x;
    int wv = threadIdx.x >> 6, lane = threadIdx.x & 63;
    int len = min(cnt[r], CAP), base = r*CAP;
    int q0 = (len*wv) >> 2, q1 = (len*(wv+1)) >> 2;
    float a0=0.f,a1=0.f,p0=0.f,p1=0.f, sv0=0.f, sv1=0.f;
    int j = q0;
    for (; j+2 <= q1; j += 2) {
        int cA = ecol[base+j], cB = ecol[base+j+1];
        float4 eA = ev4[base+j], eB = ev4[base+j+1];
        float2 xA = H12[cA*64+lane], xB = H12[cB*64+lane];
        float2 sA = s02[cA], sB = s02[cB];
        a0 += eA.z*xA.x; p0 += eA.w*xA.y;
        a1 += eB.z*xB.x; p1 += eB.w*xB.y;
        sv0 += eA.z*sA.x + eB.z*sB.x;
        sv1 += eA.w*sA.y + eB.w*sB.y;
    }
    if (j < q1) {
        int cA = ecol[base+j]; float4 eA = ev4[base+j];
        float2 xA = H12[cA*64+lane]; float2 sA = s02[cA];
        a0 += eA.z*xA.x; p0 += eA.w*xA.y;
        sv0 += eA.z*sA.x; sv1 += eA.w*sA.y;
    }
    redA[wv][lane] = a0+a1; redP[wv][lane] = p0+p1;
    if (lane == 0) { rv[wv][0] = sv0; rv[wv][1] = sv1; }
    __syncthreads();
    if (wv == 0) {
        float A = redA[0][lane]+redA[1][lane]+redA[2][lane]+redA[3][lane];
        float P = redP[0][lane]+redP[1][lane]+redP[2][lane]+redP[3][lane];
        float SV0 = rv[0][0]+rv[1][0]+rv[2][0]+rv[3][0];
        float SV1 = rv[0][1]+rv[1][1]+rv[2][1]+rv[3][1];
        float dv = rsqrtf(1.0f + SV0 + SV1);
        float2 x = Xp2[r*64 + lane];
        float hc = 0.5f*(fmaxf(0.5f*(x.x + A), 0.f) + fmaxf(0.5f*(x.y + P), 0.f));
        if (lane == 0) dinv[r] = dv;
        int jj = lane & 15, quarter = lane >> 4;
        float acc = 0.f;
        #pragma unroll
        for (int k = 0; k < 16; k++) {
            int d = quarter*16 + k;
            acc += __shfl(hc, d) * w1[d*16 + jj];
        }
        acc += __shfl_xor(acc, 16);
        acc += __shfl_xor(acc, 32);
        if (lane < 16) M1d[r*16 + lane] = dv * acc;
    }
}

// ---------------- GCN16 pass 1: U = M0 @ M1d (per channel) ----------------
__global__ __launch_bounds__(256) void k_g1a(
    const int* __restrict__ cnt, const int* __restrict__ ecol,
    const float4* __restrict__ ev4, const float* __restrict__ M1d,
    float* __restrict__ U2) {
    __shared__ float red[4][32];
    int r = blockIdx.x;
    int wv = threadIdx.x >> 6, lane = threadIdx.x & 63;
    int d = lane & 15, ch = (lane >> 4) & 1, ep = lane >> 5;
    int len = min(cnt[r], CAP), base = r*CAP;
    int q0 = (len*wv) >> 2, q1 = (len*(wv+1)) >> 2;
    float acc = 0.f;
    int j = q0;
    for (; j+2 <= q1; j += 2) {
        int jj = base + j + ep;
        int c = ecol[jj]; float4 e = ev4[jj];
        acc += (ch ? e.y : e.x) * M1d[c*16 + d];
    }
    if (j < q1 && ep == 0) {
        int c = ecol[base+j]; float4 e = ev4[base+j];
        acc += (ch ? e.y : e.x) * M1d[c*16 + d];
    }
    acc += __shfl_xor(acc, 32);
    if (lane < 32) red[wv][lane] = acc;
    __syncthreads();
    if (wv == 0 && lane < 32) {
        float s = red[0][lane]+red[1][lane]+red[2][lane]+red[3][lane];
        U2[r*32 + d*2 + ch] = s;
    }
}

// ---------------- GCN16 pass 2 fused: P = M1 @ U, h1 = relu, M2d = dinv*(h1@w2) ----------------
__global__ __launch_bounds__(256) void k_g1b(
    const int* __restrict__ cnt, const int* __restrict__ ecol,
    const float4* __restrict__ ev4, const float* __restrict__ U2,
    const float* __restrict__ M1d, const float* __restrict__ dinv,
    const float* __restrict__ b1, const float* __restrict__ w2,
    float* __restrict__ M2d) {
    __shared__ float red[4][32];
    int r = blockIdx.x;
    int wv = threadIdx.x >> 6, lane = threadIdx.x & 63;
    int d = lane & 15, ch = (lane >> 4) & 1, ep = lane >> 5;
    int len = min(cnt[r], CAP), base = r*CAP;
    int q0 = (len*wv) >> 2, q1 = (len*(wv+1)) >> 2;
    float acc = 0.f;
    int j = q0;
    for (; j+2 <= q1; j += 2) {
        int jj = base + j + ep;
        int c = ecol[jj]; float4 e = ev4[jj];
        acc += (ch ? e.w : e.z) * U2[c*32 + d*2 + ch];
    }
    if (j < q1 && ep == 0) {
        int c = ecol[base+j]; float4 e = ev4[base+j];
        acc += (ch ? e.w : e.z) * U2[c*32 + d*2 + ch];
    }
    acc += __shfl_xor(acc, 32);
    if (lane < 32) red[wv][lane] = acc;
    __syncthreads();
    if (wv == 0) {
        float Pv = red[0][lane&31]+red[1][lane&31]+red[2][lane&31]+red[3][lane&31];
        Pv += __shfl_xor(Pv, 16);
        float dv = dinv[r];
        float hv = fmaxf(dv*(Pv + M1d[r*16 + (lane&15)]) + b1[lane&15], 0.f);
        float m2 = 0.f;
        #pragma unroll
        for (int k = 0; k < 16; k++) m2 += __shfl(hv, k) * w2[k*64 + lane];
        M2d[r*64 + lane] = dv * m2;
    }
}

// ---------------- GCN64 pass 1: V = M0 @ M2d (shared x, both ch) ----------------
__global__ __launch_bounds__(256) void k_g2a(
    const int* __restrict__ cnt, const int* __restrict__ ecol,
    const float4* __restrict__ ev4, const float* __restrict__ M2d,
    float2* __restrict__ V2) {
    __shared__ float redA[4][64], redP[4][64];
    int r = blockIdx.x;
    int wv = threadIdx.x >> 6, lane = threadIdx.x & 63;
    int len = min(cnt[r], CAP), base = r*CAP;
    int q0 = (len*wv) >> 2, q1 = (len*(wv+1)) >> 2;
    float a0=0.f,a1=0.f,p0=0.f,p1=0.f;
    int j = q0;
    for (; j+2 <= q1; j += 2) {
        int cA = ecol[base+j], cB = ecol[base+j+1];
        float4 eA = ev4[base+j], eB = ev4[base+j+1];
        float xA = M2d[cA*64+lane], xB = M2d[cB*64+lane];
        a0 += eA.x*xA; p0 += eA.y*xA;
        a1 += eB.x*xB; p1 += eB.y*xB;
    }
    if (j < q1) {
        int cA = ecol[base+j]; float4 eA = ev4[base+j];
        float xA = M2d[cA*64+lane];
        a0 += eA.x*xA; p0 += eA.y*xA;
    }
    redA[wv][lane] = a0+a1; redP[wv][lane] = p0+p1;
    __syncthreads();
    if (wv == 0) {
        float A = redA[0][lane]+redA[1][lane]+redA[2][lane]+redA[3][lane];
        float P = redP[0][lane]+redP[1][lane]+redP[2][lane]+redP[3][lane];
        V2[r*64 + lane] = make_float2(A, P);
    }
}

// ---------------- GCN64 pass 2 fused: R = M1 @ V, log_softmax, head for matching targets ----------------
__global__ __launch_bounds__(256) void k_g2b(
    const int* __restrict__ cnt, const int* __restrict__ ecol,
    const float4* __restrict__ ev4, const float2* __restrict__ V2,
    const float* __restrict__ M2d, const float* __restrict__ dinv,
    const float* __restrict__ b2, const int* __restrict__ tgt,
    const float* __restrict__ lin_w, const float* __restrict__ lin_b,
    float* __restrict__ out) {
    __shared__ float red[4][64];
    __shared__ float hsh[64];
    int r = blockIdx.x;
    int wv = threadIdx.x >> 6, lane = threadIdx.x & 63;
    int len = min(cnt[r], CAP), base = r*CAP;
    int q0 = (len*wv) >> 2, q1 = (len*(wv+1)) >> 2;
    float a0=0.f, a1=0.f;
    int j = q0;
    for (; j+2 <= q1; j += 2) {
        int cA = ecol[base+j], cB = ecol[base+j+1];
        float4 eA = ev4[base+j], eB = ev4[base+j+1];
        float2 xA = V2[cA*64+lane], xB = V2[cB*64+lane];
        a0 += eA.z*xA.x + eA.w*xA.y;
        a1 += eB.z*xB.x + eB.w*xB.y;
    }
    if (j < q1) {
        int cA = ecol[base+j]; float4 eA = ev4[base+j];
        float2 xA = V2[cA*64+lane];
        a0 += eA.z*xA.x + eA.w*xA.y;
    }
    red[wv][lane] = a0+a1;
    __syncthreads();
    if (wv == 0) {
        float S = red[0][lane]+red[1][lane]+red[2][lane]+red[3][lane];
        float v = dinv[r]*(S + M2d[r*64 + lane]) + b2[lane];
        float mx = v;
        #pragma unroll
        for (int o = 1; o < 64; o <<= 1) mx = fmaxf(mx, __shfl_xor(mx, o));
        float s = expf(v - mx);
        #pragma unroll
        for (int o = 1; o < 64; o <<= 1) s += __shfl_xor(s, o);
        hsh[lane] = v - mx - logf(s);
    }
    __syncthreads();
    // head: each thread scans 2 targets; write out rows whose target node == r
    for (int i = threadIdx.x; i < NTGT; i += 256) {
        if (tgt[i] == r) {
            #pragma unroll 4
            for (int k = 0; k < 16; k++) {
                float acc = 0.f;
                #pragma unroll
                for (int dd = 0; dd < 64; dd++) acc += hsh[dd] * lin_w[dd*16 + k];
                out[i*16 + k] = acc + lin_b[k];
            }
        }
    }
}

// ---------------- launch ----------------
extern "C" void kernel_launch(void* const* d_in, const int* in_sizes, int n_in,
                              void* d_out, int out_size, void* d_ws, size_t ws_size,
                              hipStream_t stream) {
    const float* X          = (const float*)d_in[0];
    const float* edge_value = (const float*)d_in[1];
    const float* conv_w     = (const float*)d_in[2];
    const float* Ws         = (const float*)d_in[3];
    const float* w1         = (const float*)d_in[4];
    const float* b1         = (const float*)d_in[5];
    const float* w2         = (const float*)d_in[6];
    const float* b2         = (const float*)d_in[7];
    const float* lin_w      = (const float*)d_in[8];
    const float* lin_b      = (const float*)d_in[9];
    const int*   ei         = (const int*)d_in[10];
    const int*   tgt        = (const int*)d_in[11];
    float* out = (float*)d_out;

    float* ws = (float*)d_ws;
    int*    cnt  = (int*)(ws + OFF_CNT);
    int*    ecol = (int*)(ws + OFF_ECOL);
    float4* ev4  = (float4*)(ws + OFF_EV);
    float2* Xp2  = (float2*)(ws + OFF_XP);
    float2* H12  = (float2*)(ws + OFF_H1);
    float2* s02  = (float2*)(ws + OFF_S0);
    float*  dinv = ws + OFF_DINV;
    float*  M1d  = ws + OFF_M1D;
    float*  U2   = ws + OFF_U;
    float*  M2d  = ws + OFF_M2D;
    float2* V2   = (float2*)(ws + OFF_V);

    hipMemsetAsync(cnt, 0, N_NODES*sizeof(int), stream);
    k_init<<<896, 256, 0, stream>>>(conv_w, X, Ws, ei, edge_value, cnt, ecol, ev4, Xp2);
    k_h0  <<<N_NODES, 256, 0, stream>>>(cnt, ecol, ev4, Xp2, H12, s02);
    k_h1  <<<N_NODES, 256, 0, stream>>>(cnt, ecol, ev4, H12, s02, Xp2, w1, dinv, M1d);
    k_g1a <<<N_NODES, 256, 0, stream>>>(cnt, ecol, ev4, M1d, U2);
    k_g1b <<<N_NODES, 256, 0, stream>>>(cnt, ecol, ev4, U2, M1d, dinv, b1, w2, M2d);
    k_g2a <<<N_NODES, 256, 0, stream>>>(cnt, ecol, ev4, M2d, V2);
    k_g2b <<<N_NODES, 256, 0, stream>>>(cnt, ecol, ev4, V2, M2d, dinv, b2, tgt, lin_w, lin_b, out);
}